// Round 3
// baseline (322.368 us; speedup 1.0000x reference)
//
#include <hip/hip_runtime.h>
#include <hip/hip_bf16.h>

#define B_N 512
#define L_N 200
#define E_N 128
#define K_N 384
#define D_N 384

typedef __bf16 v8bf  __attribute__((ext_vector_type(8)));
typedef float  v4f   __attribute__((ext_vector_type(4)));
typedef unsigned int v4u __attribute__((ext_vector_type(4)));
typedef unsigned short v8us __attribute__((ext_vector_type(8)));

__device__ __forceinline__ unsigned short f2bf(float f) {
    union { __bf16 b; unsigned short u; } cv;
    cv.b = (__bf16)f;   // RNE
    return cv.u;
}
// tanh via v_rcp_f32 (saves the ~8-op full-precision divide sequence;
// rcp rel err ~1e-7 -> abs tanh err ~1e-6, far under tolerance headroom)
__device__ __forceinline__ float fast_tanh(float x) {
    float e = __expf(2.f * x);
    return 1.f - 2.f * __builtin_amdgcn_rcpf(e + 1.f);
}

// Wp layout (PROVEN R2/R4/R5): frag (kk in [0,12), gn in [0,24)) at
// ((kk*24+gn)*64+lane)*8 bf16 = W[n=gn*16+(lane&15)][k=kk*32+(lane>>4)*8 ..+7]
__global__ void pack_w(const float* __restrict__ W, unsigned short* __restrict__ Wp) {
    int gid  = blockIdx.x * 256 + threadIdx.x;   // 18432
    int lane = gid & 63;
    int u    = gid >> 6;                         // [0,288)
    int gn   = u % 24;
    int kk   = u / 24;
    int c    = lane & 15, quad = lane >> 4;
    const float* src = W + (gn * 16 + c) * K_N + kk * 32 + quad * 8;
    ushort4 lo, hi;
    lo.x = f2bf(src[0]); lo.y = f2bf(src[1]); lo.z = f2bf(src[2]); lo.w = f2bf(src[3]);
    hi.x = f2bf(src[4]); hi.y = f2bf(src[5]); hi.z = f2bf(src[6]); hi.w = f2bf(src[7]);
    ushort4* dst = (ushort4*)(Wp + (size_t)gid * 8);
    dst[0] = lo; dst[1] = hi;
}

// Alds layout (R10): segment-major, UNPADDED, XOR-swizzled.
// elem(m, s, off_e) at  s*8192 + m*128 + (off_e ^ ((m&7)<<3)),   off_e in [0,128)
// 64 rows x 384 k x bf16 = 49152 B (vs 50176 padded) -> block LDS 53696 B
// -> 3 blocks/CU (was 2). Swizzle keeps ds_read_b128 at the even 8-access/bank
// minimum (verified: bank = f(off^((c&7)<<4)) spans all 32 banks evenly).
#define SEG_E 8192   // elems per segment (64 rows * 128)

// MFMA + tanh + score partials for one chunk; MT = number of 16-row M-tiles
// (4 for full 64-row chunks, 1 for the 16-row tail covering rows 192..199).
template<int MT>
__device__ __forceinline__ void compute_chunk(
    const unsigned short* Alds, const v4u* wp4, float (*sp)[64],
    int wv, int lane, int quad, int c,
    float an0, float an1, float an2,
    v4f (&acc)[4][3])
{
    const int arow = c * 128;          // row base (elems) within a segment
    const int akey = (c & 7) << 3;     // swizzle key (elems)
    const int q8   = quad * 8;

    #pragma unroll 2
    for (int kk = 0; kk < 12; ++kk) {
        v8bf b0 = __builtin_bit_cast(v8bf, wp4[(kk * 24 + wv * 3 + 0) * 64 + lane]);
        v8bf b1 = __builtin_bit_cast(v8bf, wp4[(kk * 24 + wv * 3 + 1) * 64 + lane]);
        v8bf b2 = __builtin_bit_cast(v8bf, wp4[(kk * 24 + wv * 3 + 2) * 64 + lane]);
        // k0 = kk*32 + quad*8; seg = k0>>7 = kk>>2 (uniform per instr);
        // in-row elem off = (k0&127) ^ akey, with (kk&3)*32 + q8 < 128.
        const int soff = (((kk & 3) * 32 + q8) ^ akey);
        #pragma unroll
        for (int mt = 0; mt < MT; ++mt) {
            v8bf a = *(const v8bf*)&Alds[(kk >> 2) * SEG_E + mt * 2048 + arow + soff];
            acc[mt][0] = __builtin_amdgcn_mfma_f32_16x16x32_bf16(a, b0, acc[mt][0], 0, 0, 0);
            acc[mt][1] = __builtin_amdgcn_mfma_f32_16x16x32_bf16(a, b1, acc[mt][1], 0, 0, 0);
            acc[mt][2] = __builtin_amdgcn_mfma_f32_16x16x32_bf16(a, b2, acc[mt][2], 0, 0, 0);
        }
    }
    // tanh + per-wave score partials (all-constant indexing)
    #pragma unroll
    for (int mt = 0; mt < MT; ++mt) {
        #pragma unroll
        for (int r = 0; r < 4; ++r) {
            float h0 = fast_tanh(acc[mt][0][r]);
            float h1 = fast_tanh(acc[mt][1][r]);
            float h2 = fast_tanh(acc[mt][2][r]);
            acc[mt][0][r] = h0; acc[mt][1][r] = h1; acc[mt][2][r] = h2;
            float sv = h0 * an0 + h1 * an1 + h2 * an2;
            sv += __shfl_xor(sv, 1);
            sv += __shfl_xor(sv, 2);
            sv += __shfl_xor(sv, 4);
            sv += __shfl_xor(sv, 8);
            if (c == 0) sp[wv][mt * 16 + quad * 4 + r] = sv;
        }
    }
}

// One block per (b, pass); 512 threads = 8 waves; wave owns cols wv*48..+47.
// M in chunks {64,64,64,16} (rows >= 200 masked via -1e30 score -> weight 0).
// R10 = R9 + unpadded swizzled Alds: LDS 54784 -> 53696 B => 3 blocks/CU
// (75% occupancy target). All arithmetic identical to R9.
__global__ __launch_bounds__(512, 6)
void c2v_fused(const int* __restrict__ xs1, const int* __restrict__ ph1,
               const int* __restrict__ xt1,
               const int* __restrict__ xs2, const int* __restrict__ ph2,
               const int* __restrict__ xt2,
               const float* __restrict__ wemb, const float* __restrict__ pemb,
               const unsigned short* __restrict__ Wp,
               const float* __restrict__ attn,
               float* __restrict__ out)
{
    const int tid  = threadIdx.x;
    const int wv   = tid >> 6;
    const int lane = tid & 63;
    const int quad = lane >> 4;
    const int c    = lane & 15;
    const int b    = blockIdx.x;
    const int pass = blockIdx.y;

    const int* xs = pass ? xs2 : xs1;
    const int* ph = pass ? ph2 : ph1;
    const int* xt = pass ? xt2 : xt1;

    __shared__ __align__(16) unsigned short Alds[3 * SEG_E];   // 49152 B
    __shared__ float sp[8][64];                                // 2048 B
    __shared__ int   ilds[3 * 208];                            // 2496 B

    for (int u = tid; u < 624; u += 512) {
        int s = u / 208, g = u - s * 208;
        const int* tab = (s == 0) ? xs : (s == 1) ? ph : xt;
        ilds[u] = (g < L_N) ? tab[b * L_N + g] : 0;
    }

    const float an0 = attn[(wv * 3 + 0) * 16 + c];
    const float an1 = attn[(wv * 3 + 1) * 16 + c];
    const float an2 = attn[(wv * 3 + 2) * 16 + c];

    float o0 = 0.f, o1 = 0.f, o2 = 0.f;   // running unnormalized col sums
    float Mrun = -1e30f, Zrun = 0.f;      // softmax state (identical in every thread)

    const v4u* wp4 = (const v4u*)Wp;

    __syncthreads();   // ilds visible before first staging loads

    for (int chunk = 0; chunk < 4; ++chunk) {
        const int row0  = chunk * 64;
        const int mrows = (chunk == 3) ? 16 : 64;
        const int mtmax = (chunk == 3) ? 1 : 4;

        // ---- staging: all 12 loads issued back-to-back (acc is dead here),
        // converted to bf16 in regs; lifetime ends at the LDS store below.
        float4 fa[6], fb[6];
        #pragma unroll
        for (int i = 0; i < 6; ++i) {
            int u = i * 512 + tid;
            int s = u >> 10;            // seg 0..2 (1024 units per seg)
            int rr = u & 1023;
            int m = rr >> 4;            // row within chunk, 0..63
            int j = rr & 15;            // 8-elem unit within seg, 0..15
            int g = row0 + m;
            if (m < mrows && g < L_N) {
                const float* eb = (s == 1) ? pemb : wemb;
                const float* src = eb + (size_t)ilds[s * 208 + g] * E_N + j * 8;
                fa[i] = *(const float4*)src;
                fb[i] = *(const float4*)(src + 4);
            } else {
                fa[i].x = fa[i].y = fa[i].z = fa[i].w = 0.f;
                fb[i] = fa[i];
            }
        }
        v8us cv[6];
        #pragma unroll
        for (int i = 0; i < 6; ++i) {
            cv[i][0] = f2bf(fa[i].x); cv[i][1] = f2bf(fa[i].y);
            cv[i][2] = f2bf(fa[i].z); cv[i][3] = f2bf(fa[i].w);
            cv[i][4] = f2bf(fb[i].x); cv[i][5] = f2bf(fb[i].y);
            cv[i][6] = f2bf(fb[i].z); cv[i][7] = f2bf(fb[i].w);
        }

        __syncthreads();   // previous chunk's Alds/sp fully consumed

        #pragma unroll
        for (int i = 0; i < 6; ++i) {
            int u = i * 512 + tid;
            int s = u >> 10, rr = u & 1023, m = rr >> 4, j = rr & 15;
            if (m < mrows)   // swizzled store: off = (j*8) ^ ((m&7)<<3)
                *(v8us*)&Alds[s * SEG_E + m * 128 + ((j * 8) ^ ((m & 7) << 3))] = cv[i];
        }
        __syncthreads();

        v4f acc[4][3];
        #pragma unroll
        for (int i = 0; i < 4; ++i)
            #pragma unroll
            for (int j = 0; j < 3; ++j)
                acc[i][j] = (v4f){0.f, 0.f, 0.f, 0.f};

        if (chunk < 3)
            compute_chunk<4>(Alds, wp4, sp, wv, lane, quad, c, an0, an1, an2, acc);
        else
            compute_chunk<1>(Alds, wp4, sp, wv, lane, quad, c, an0, an1, an2, acc);
        __syncthreads();   // sp complete

        // ---- redundant all-wave softmax (deterministic -> identical in all waves)
        {
            int g = row0 + lane;
            float s = sp[0][lane] + sp[1][lane] + sp[2][lane] + sp[3][lane]
                    + sp[4][lane] + sp[5][lane] + sp[6][lane] + sp[7][lane];
            if (g >= L_N) s = -1e30f;   // also kills stale sp rows in tail chunk
            float mx = s;
            #pragma unroll
            for (int off = 32; off > 0; off >>= 1) mx = fmaxf(mx, __shfl_xor(mx, off));
            float Mnew  = fmaxf(Mrun, mx);
            float alpha = __expf(Mrun - Mnew);
            float e = (g < L_N) ? __expf(s - Mnew) : 0.f;
            float zc = e;
            #pragma unroll
            for (int off = 32; off > 0; off >>= 1) zc += __shfl_xor(zc, off);
            Zrun = Zrun * alpha + zc;
            Mrun = Mnew;

            // rescale running O, add this chunk's weighted rows; weights via
            // intra-wave shuffle (e lives in lane == row-within-chunk)
            float p0 = 0.f, p1 = 0.f, p2 = 0.f;
            #pragma unroll
            for (int mt = 0; mt < 4; ++mt) {
                if (mt < mtmax) {
                    #pragma unroll
                    for (int r = 0; r < 4; ++r) {
                        float w = __shfl(e, mt * 16 + quad * 4 + r);
                        p0 += w * acc[mt][0][r];
                        p1 += w * acc[mt][1][r];
                        p2 += w * acc[mt][2][r];
                    }
                }
            }
            o0 = o0 * alpha + p0;
            o1 = o1 * alpha + p1;
            o2 = o2 * alpha + p2;
        }
    }

    // Zrun is identical in every thread -- no broadcast needed
    const float zinv = __builtin_amdgcn_rcpf(Zrun);

    float* outp = out + (size_t)(pass * B_N + b) * D_N;
    o0 += __shfl_xor(o0, 16); o0 += __shfl_xor(o0, 32);
    o1 += __shfl_xor(o1, 16); o1 += __shfl_xor(o1, 32);
    o2 += __shfl_xor(o2, 16); o2 += __shfl_xor(o2, 32);
    if (quad == 0) {
        outp[(wv * 3 + 0) * 16 + c] = o0 * zinv;
        outp[(wv * 3 + 1) * 16 + c] = o1 * zinv;
        outp[(wv * 3 + 2) * 16 + c] = o2 * zinv;
    }
}

extern "C" void kernel_launch(void* const* d_in, const int* in_sizes, int n_in,
                              void* d_out, int out_size, void* d_ws, size_t ws_size,
                              hipStream_t stream) {
    unsigned short* Wp = (unsigned short*)d_ws;   // 294912 B
    pack_w<<<72, 256, 0, stream>>>((const float*)d_in[8], Wp);
    dim3 grid(B_N, 2, 1);
    c2v_fused<<<grid, 512, 0, stream>>>(
        (const int*)d_in[0], (const int*)d_in[1], (const int*)d_in[2],
        (const int*)d_in[3], (const int*)d_in[4], (const int*)d_in[5],
        (const float*)d_in[6], (const float*)d_in[7],
        Wp, (const float*)d_in[9],
        (float*)d_out);
}

// Round 4
// 288.220 us; speedup vs baseline: 1.1185x; 1.1185x over previous
//
#include <hip/hip_runtime.h>
#include <hip/hip_bf16.h>

#define B_N 512
#define L_N 200
#define E_N 128
#define K_N 384
#define D_N 384

typedef __bf16 v8bf  __attribute__((ext_vector_type(8)));
typedef float  v4f   __attribute__((ext_vector_type(4)));
typedef unsigned int v4u __attribute__((ext_vector_type(4)));
typedef unsigned short v8us __attribute__((ext_vector_type(8)));

__device__ __forceinline__ unsigned short f2bf(float f) {
    union { __bf16 b; unsigned short u; } cv;
    cv.b = (__bf16)f;   // RNE
    return cv.u;
}
// tanh via v_rcp_f32 (saves the ~8-op full-precision divide sequence;
// rcp rel err ~1e-7 -> abs tanh err ~1e-6, far under tolerance headroom)
__device__ __forceinline__ float fast_tanh(float x) {
    float e = __expf(2.f * x);
    return 1.f - 2.f * __builtin_amdgcn_rcpf(e + 1.f);
}

// Wp layout (PROVEN R2/R4/R5): frag (kk in [0,12), gn in [0,24)) at
// ((kk*24+gn)*64+lane)*8 bf16 = W[n=gn*16+(lane&15)][k=kk*32+(lane>>4)*8 ..+7]
__global__ void pack_w(const float* __restrict__ W, unsigned short* __restrict__ Wp) {
    int gid  = blockIdx.x * 256 + threadIdx.x;   // 18432
    int lane = gid & 63;
    int u    = gid >> 6;                         // [0,288)
    int gn   = u % 24;
    int kk   = u / 24;
    int c    = lane & 15, quad = lane >> 4;
    const float* src = W + (gn * 16 + c) * K_N + kk * 32 + quad * 8;
    ushort4 lo, hi;
    lo.x = f2bf(src[0]); lo.y = f2bf(src[1]); lo.z = f2bf(src[2]); lo.w = f2bf(src[3]);
    hi.x = f2bf(src[4]); hi.y = f2bf(src[5]); hi.z = f2bf(src[6]); hi.w = f2bf(src[7]);
    ushort4* dst = (ushort4*)(Wp + (size_t)gid * 8);
    dst[0] = lo; dst[1] = hi;
}

// Alds layout (R10, kept): segment-major, UNPADDED, XOR-swizzled.
// elem(m, s, off_e) at  s*8192 + m*128 + (off_e ^ ((m&7)<<3)),   off_e in [0,128)
// 64 rows x 384 k x bf16 = 49152 B -> block LDS 53696 B -> 3 blocks/CU.
// Swizzle keeps ds_read_b128/ds_write_b128 at the even 8-access/bank minimum
// (R10 confirmed: SQ_LDS_BANK_CONFLICT identical to the padded layout).
#define SEG_E 8192   // elems per segment (64 rows * 128)

// MFMA + tanh + score partials for one chunk; MT = number of 16-row M-tiles
// (4 for full 64-row chunks, 1 for the 16-row tail covering rows 192..199).
template<int MT>
__device__ __forceinline__ void compute_chunk(
    const unsigned short* Alds, const v4u* wp4, float (*sp)[64],
    int wv, int lane, int quad, int c,
    float an0, float an1, float an2,
    v4f (&acc)[4][3])
{
    const int arow = c * 128;          // row base (elems) within a segment
    const int akey = (c & 7) << 3;     // swizzle key (elems)
    const int q8   = quad * 8;

    #pragma unroll 2
    for (int kk = 0; kk < 12; ++kk) {
        v8bf b0 = __builtin_bit_cast(v8bf, wp4[(kk * 24 + wv * 3 + 0) * 64 + lane]);
        v8bf b1 = __builtin_bit_cast(v8bf, wp4[(kk * 24 + wv * 3 + 1) * 64 + lane]);
        v8bf b2 = __builtin_bit_cast(v8bf, wp4[(kk * 24 + wv * 3 + 2) * 64 + lane]);
        // k0 = kk*32 + quad*8; seg = kk>>2 (uniform per instr);
        // in-row elem off = ((kk&3)*32 + q8) ^ akey  (< 128).
        const int soff = (((kk & 3) * 32 + q8) ^ akey);
        #pragma unroll
        for (int mt = 0; mt < MT; ++mt) {
            v8bf a = *(const v8bf*)&Alds[(kk >> 2) * SEG_E + mt * 2048 + arow + soff];
            acc[mt][0] = __builtin_amdgcn_mfma_f32_16x16x32_bf16(a, b0, acc[mt][0], 0, 0, 0);
            acc[mt][1] = __builtin_amdgcn_mfma_f32_16x16x32_bf16(a, b1, acc[mt][1], 0, 0, 0);
            acc[mt][2] = __builtin_amdgcn_mfma_f32_16x16x32_bf16(a, b2, acc[mt][2], 0, 0, 0);
        }
    }
    // tanh + per-wave score partials (all-constant indexing)
    #pragma unroll
    for (int mt = 0; mt < MT; ++mt) {
        #pragma unroll
        for (int r = 0; r < 4; ++r) {
            float h0 = fast_tanh(acc[mt][0][r]);
            float h1 = fast_tanh(acc[mt][1][r]);
            float h2 = fast_tanh(acc[mt][2][r]);
            acc[mt][0][r] = h0; acc[mt][1][r] = h1; acc[mt][2][r] = h2;
            float sv = h0 * an0 + h1 * an1 + h2 * an2;
            sv += __shfl_xor(sv, 1);
            sv += __shfl_xor(sv, 2);
            sv += __shfl_xor(sv, 4);
            sv += __shfl_xor(sv, 8);
            if (c == 0) sp[wv][mt * 16 + quad * 4 + r] = sv;
        }
    }
}

// One block per (b, pass); 512 threads = 8 waves; wave owns cols wv*48..+47.
// M in chunks {64,64,64,16} (rows >= 200 masked via -1e30 score -> weight 0).
// R11 = R10 but launch_bounds back to (512,4): empirically the 2nd arg caps
// VGPR at ~256/arg on this compiler (R10's arg=6 capped at 40 -> 81 MB of
// scratch spill). arg=4 -> cap 64, proven spill-free in R9. With VGPR=64
// (8 waves/SIMD worth) occupancy is LDS-limited at 3 blocks/CU (53696 B x 3).
__global__ __launch_bounds__(512, 4)
void c2v_fused(const int* __restrict__ xs1, const int* __restrict__ ph1,
               const int* __restrict__ xt1,
               const int* __restrict__ xs2, const int* __restrict__ ph2,
               const int* __restrict__ xt2,
               const float* __restrict__ wemb, const float* __restrict__ pemb,
               const unsigned short* __restrict__ Wp,
               const float* __restrict__ attn,
               float* __restrict__ out)
{
    const int tid  = threadIdx.x;
    const int wv   = tid >> 6;
    const int lane = tid & 63;
    const int quad = lane >> 4;
    const int c    = lane & 15;
    const int b    = blockIdx.x;
    const int pass = blockIdx.y;

    const int* xs = pass ? xs2 : xs1;
    const int* ph = pass ? ph2 : ph1;
    const int* xt = pass ? xt2 : xt1;

    __shared__ __align__(16) unsigned short Alds[3 * SEG_E];   // 49152 B
    __shared__ float sp[8][64];                                // 2048 B
    __shared__ int   ilds[3 * 208];                            // 2496 B

    for (int u = tid; u < 624; u += 512) {
        int s = u / 208, g = u - s * 208;
        const int* tab = (s == 0) ? xs : (s == 1) ? ph : xt;
        ilds[u] = (g < L_N) ? tab[b * L_N + g] : 0;
    }

    const float an0 = attn[(wv * 3 + 0) * 16 + c];
    const float an1 = attn[(wv * 3 + 1) * 16 + c];
    const float an2 = attn[(wv * 3 + 2) * 16 + c];

    float o0 = 0.f, o1 = 0.f, o2 = 0.f;   // running unnormalized col sums
    float Mrun = -1e30f, Zrun = 0.f;      // softmax state (identical in every thread)

    const v4u* wp4 = (const v4u*)Wp;

    __syncthreads();   // ilds visible before first staging loads

    for (int chunk = 0; chunk < 4; ++chunk) {
        const int row0  = chunk * 64;
        const int mrows = (chunk == 3) ? 16 : 64;
        const int mtmax = (chunk == 3) ? 1 : 4;

        // ---- staging: all 12 loads issued back-to-back (acc is dead here),
        // converted to bf16 in regs; lifetime ends at the LDS store below.
        float4 fa[6], fb[6];
        #pragma unroll
        for (int i = 0; i < 6; ++i) {
            int u = i * 512 + tid;
            int s = u >> 10;            // seg 0..2 (1024 units per seg)
            int rr = u & 1023;
            int m = rr >> 4;            // row within chunk, 0..63
            int j = rr & 15;            // 8-elem unit within seg, 0..15
            int g = row0 + m;
            if (m < mrows && g < L_N) {
                const float* eb = (s == 1) ? pemb : wemb;
                const float* src = eb + (size_t)ilds[s * 208 + g] * E_N + j * 8;
                fa[i] = *(const float4*)src;
                fb[i] = *(const float4*)(src + 4);
            } else {
                fa[i].x = fa[i].y = fa[i].z = fa[i].w = 0.f;
                fb[i] = fa[i];
            }
        }
        v8us cv[6];
        #pragma unroll
        for (int i = 0; i < 6; ++i) {
            cv[i][0] = f2bf(fa[i].x); cv[i][1] = f2bf(fa[i].y);
            cv[i][2] = f2bf(fa[i].z); cv[i][3] = f2bf(fa[i].w);
            cv[i][4] = f2bf(fb[i].x); cv[i][5] = f2bf(fb[i].y);
            cv[i][6] = f2bf(fb[i].z); cv[i][7] = f2bf(fb[i].w);
        }

        __syncthreads();   // previous chunk's Alds/sp fully consumed

        #pragma unroll
        for (int i = 0; i < 6; ++i) {
            int u = i * 512 + tid;
            int s = u >> 10, rr = u & 1023, m = rr >> 4, j = rr & 15;
            if (m < mrows)   // swizzled store: off = (j*8) ^ ((m&7)<<3)
                *(v8us*)&Alds[s * SEG_E + m * 128 + ((j * 8) ^ ((m & 7) << 3))] = cv[i];
        }
        __syncthreads();

        v4f acc[4][3];
        #pragma unroll
        for (int i = 0; i < 4; ++i)
            #pragma unroll
            for (int j = 0; j < 3; ++j)
                acc[i][j] = (v4f){0.f, 0.f, 0.f, 0.f};

        if (chunk < 3)
            compute_chunk<4>(Alds, wp4, sp, wv, lane, quad, c, an0, an1, an2, acc);
        else
            compute_chunk<1>(Alds, wp4, sp, wv, lane, quad, c, an0, an1, an2, acc);
        __syncthreads();   // sp complete

        // ---- redundant all-wave softmax (deterministic -> identical in all waves)
        {
            int g = row0 + lane;
            float s = sp[0][lane] + sp[1][lane] + sp[2][lane] + sp[3][lane]
                    + sp[4][lane] + sp[5][lane] + sp[6][lane] + sp[7][lane];
            if (g >= L_N) s = -1e30f;   // also kills stale sp rows in tail chunk
            float mx = s;
            #pragma unroll
            for (int off = 32; off > 0; off >>= 1) mx = fmaxf(mx, __shfl_xor(mx, off));
            float Mnew  = fmaxf(Mrun, mx);
            float alpha = __expf(Mrun - Mnew);
            float e = (g < L_N) ? __expf(s - Mnew) : 0.f;
            float zc = e;
            #pragma unroll
            for (int off = 32; off > 0; off >>= 1) zc += __shfl_xor(zc, off);
            Zrun = Zrun * alpha + zc;
            Mrun = Mnew;

            // rescale running O, add this chunk's weighted rows; weights via
            // intra-wave shuffle (e lives in lane == row-within-chunk)
            float p0 = 0.f, p1 = 0.f, p2 = 0.f;
            #pragma unroll
            for (int mt = 0; mt < 4; ++mt) {
                if (mt < mtmax) {
                    #pragma unroll
                    for (int r = 0; r < 4; ++r) {
                        float w = __shfl(e, mt * 16 + quad * 4 + r);
                        p0 += w * acc[mt][0][r];
                        p1 += w * acc[mt][1][r];
                        p2 += w * acc[mt][2][r];
                    }
                }
            }
            o0 = o0 * alpha + p0;
            o1 = o1 * alpha + p1;
            o2 = o2 * alpha + p2;
        }
    }

    // Zrun is identical in every thread -- no broadcast needed
    const float zinv = __builtin_amdgcn_rcpf(Zrun);

    float* outp = out + (size_t)(pass * B_N + b) * D_N;
    o0 += __shfl_xor(o0, 16); o0 += __shfl_xor(o0, 32);
    o1 += __shfl_xor(o1, 16); o1 += __shfl_xor(o1, 32);
    o2 += __shfl_xor(o2, 16); o2 += __shfl_xor(o2, 32);
    if (quad == 0) {
        outp[(wv * 3 + 0) * 16 + c] = o0 * zinv;
        outp[(wv * 3 + 1) * 16 + c] = o1 * zinv;
        outp[(wv * 3 + 2) * 16 + c] = o2 * zinv;
    }
}

extern "C" void kernel_launch(void* const* d_in, const int* in_sizes, int n_in,
                              void* d_out, int out_size, void* d_ws, size_t ws_size,
                              hipStream_t stream) {
    unsigned short* Wp = (unsigned short*)d_ws;   // 294912 B
    pack_w<<<72, 256, 0, stream>>>((const float*)d_in[8], Wp);
    dim3 grid(B_N, 2, 1);
    c2v_fused<<<grid, 512, 0, stream>>>(
        (const int*)d_in[0], (const int*)d_in[1], (const int*)d_in[2],
        (const int*)d_in[3], (const int*)d_in[4], (const int*)d_in[5],
        (const float*)d_in[6], (const float*)d_in[7],
        Wp, (const float*)d_in[9],
        (float*)d_out);
}